// Round 16
// baseline (158.130 us; speedup 1.0000x reference)
//
#include <hip/hip_runtime.h>
#include <cstdint>
#include <cstddef>

typedef unsigned short u16;
typedef __attribute__((ext_vector_type(8))) short short8;
typedef __attribute__((ext_vector_type(4))) short short4v;
typedef __attribute__((ext_vector_type(8))) unsigned short ushort8v;
typedef __attribute__((ext_vector_type(4))) unsigned short ushort4v;
typedef __attribute__((ext_vector_type(4))) unsigned int uint4v;
typedef __attribute__((ext_vector_type(4))) float f32x4;

// Q is pre-scaled by 0.125 * log2(e) in the QKV GEMM epilogue, so softmax
// runs directly in the log2 domain (exp2, no per-element multiplies).
#define QSCALE 0.18033688011112042f
#define THR_L2 11.5417f   /* 8 * log2(e) defer-max threshold (T13) */

// ---- helpers -------------------------------------------------------------

__device__ __forceinline__ u16 f2bf(float f) {
  unsigned int u = __builtin_bit_cast(unsigned int, f);
  u += 0x7FFFu + ((u >> 16) & 1u);   // RNE
  return (u16)(u >> 16);
}

__device__ __forceinline__ void async16(const void* g, void* l) {
  __builtin_amdgcn_global_load_lds(
      (const __attribute__((address_space(1))) unsigned int*)g,
      (__attribute__((address_space(3))) unsigned int*)l, 16, 0, 0);
}

__device__ __forceinline__ float fmax3(float a, float b, float c) {
  float r;
  asm("v_max3_f32 %0, %1, %2, %3" : "=v"(r) : "v"(a), "v"(b), "v"(c));
  return r;
}

__device__ __forceinline__ unsigned int cvtpk(float lo, float hi) {
  unsigned int r;
  asm("v_cvt_pk_bf16_f32 %0, %1, %2" : "=v"(r) : "v"(lo), "v"(hi));
  return r;
}

// ---- fp32 -> bf16 convert (x + all 4 weights, one launch) ----------------

__global__ void cvt_all(const float* __restrict__ x, const float* __restrict__ Wq,
                        const float* __restrict__ Wk, const float* __restrict__ Wv,
                        const float* __restrict__ Wo, u16* __restrict__ out) {
  const int bid = blockIdx.x;
  const float* src;
  int i;
  size_t doff;
  if (bid < 8192) {               // x: 8.39M elems
    i = bid * 1024 + threadIdx.x * 4;
    src = x;
    doff = (size_t)i;
  } else {                        // weights: 4 x 1M elems
    const int k = bid - 8192;
    const int wsel = k >> 10;
    i = (k & 1023) * 1024 + threadIdx.x * 4;
    src = (wsel == 0) ? Wq : (wsel == 1) ? Wk : (wsel == 2) ? Wv : Wo;
    doff = 8388608 + (size_t)wsel * 1048576 + i;
  }
  float4 v = *(const float4*)(src + i);
  ushort4v o;
  o[0] = f2bf(v.x); o[1] = f2bf(v.y); o[2] = f2bf(v.z); o[3] = f2bf(v.w);
  *(ushort4v*)(out + doff) = o;
}

// ---- bf16 GEMM, 128x128 tile, 256 threads, 3-buffer counted-vmcnt --------
// C[M,N] = A[M,K] * W[N,K]^T. BM=BN=128, BK=32, 4 waves (2M x 2N), per-wave
// 64x64 (acc 64 AGPR + ~60 VGPR = 124 unified; launch_bounds(256,3) -> cap
// 168, no spill). 3 LDS buffers (48 KB -> 3 resident blocks/CU = 12 waves);
// gemm_tb schedule verbatim: vmcnt(4) at phase heads (4 loads/thread/stage),
// STAGE(T+2) into buf (T-1)%3 after the barrier, one barrier per K-tile.
// QKV grid 24x64 = 1536 = 6/CU = two balanced rounds of 3 (no solo tail).
// MODE 0: fused QKV — Q/K -> [B,H,S,HD] bf16 (Q x QSCALE); V -> VT-perm.
// MODE 1: f32 output [M,N] (o-proj; grid 8x64 = 512 = 2/CU balanced).

template<int MODE>
__global__ __launch_bounds__(256, 3) void gemm_t3(
    const u16* __restrict__ A, const u16* __restrict__ Bw,
    void* __restrict__ Cout, int M, int N, int K)
{
  const int t = threadIdx.x;
  const int lane = t & 63, w = t >> 6;        // 4 waves
  const int li = lane & 15, g = lane >> 4;
  const int wm = w >> 1, wn = w & 1;          // 2M x 2N

  // T1: XCD-aware block swizzle (nwg % 8 == 0)
  const int nx = gridDim.x;
  const int hwid = blockIdx.y * nx + blockIdx.x;
  const int cpx = (nx * gridDim.y) >> 3;
  const int lid = (hwid & 7) * cpx + (hwid >> 3);
  const int brow = (lid / nx) * 128, bcol = (lid % nx) * 128;

  __shared__ u16 As[3][128 * 32];   // 24 KB
  __shared__ u16 Bs[3][128 * 32];   // 24 KB

  f32x4 acc[4][4];
#pragma unroll
  for (int i = 0; i < 4; ++i)
#pragma unroll
    for (int j = 0; j < 4; ++j) acc[i][j] = f32x4{0.f, 0.f, 0.f, 0.f};

  // Staging: linear LDS dest (global_load_lds), source column pre-swizzled
  // by byte ^= ((row>>1)&3)<<4 (2-way-free on 64B rows; rule #21 pairing).
  auto STAGE = [&](int T) {
    const int b = T % 3;
    const int k0 = T * 32;
#pragma unroll
    for (int L = 0; L < 2; ++L) {
      const int f2 = t + 256 * L;              // 0..511
      const int row = f2 >> 2;                 // 0..127
      const int cb = ((f2 & 3) * 16) ^ (((row >> 1) & 3) << 4);
      async16(A + (size_t)(brow + row) * K + k0 + (cb >> 1), &As[b][f2 * 8]);
      async16(Bw + (size_t)(bcol + row) * K + k0 + (cb >> 1), &Bs[b][f2 * 8]);
    }
  };

  STAGE(0); STAGE(1);

  const int NT = K >> 5;                       // 32 K-tiles
  const int ksw = (g * 8) ^ (((li >> 1) & 3) << 3);   // element-space read swz

#pragma unroll 1
  for (int T = 0; T < NT; ++T) {
    // counted vmcnt: tile T's 4 loads landed; tile T+1's 4 may remain
    if (T < NT - 1) asm volatile("s_waitcnt vmcnt(4)" ::: "memory");
    else            asm volatile("s_waitcnt vmcnt(0)" ::: "memory");
    asm volatile("s_barrier" ::: "memory");    // tile T landed; buf (T-1)%3 free
    const int b = T % 3;
    short8 af[4], bfr[4];
#pragma unroll
    for (int mt = 0; mt < 4; ++mt)
      af[mt] = *(const short8*)&As[b][(wm * 64 + mt * 16 + li) * 32 + ksw];
#pragma unroll
    for (int nt = 0; nt < 4; ++nt)
      bfr[nt] = *(const short8*)&Bs[b][(wn * 64 + nt * 16 + li) * 32 + ksw];

    if (T + 2 < NT) STAGE(T + 2);              // into buf (T-1)%3 — safe

    __builtin_amdgcn_s_setprio(1);
#pragma unroll
    for (int mt = 0; mt < 4; ++mt)
#pragma unroll
      for (int nt = 0; nt < 4; ++nt)
        acc[mt][nt] = __builtin_amdgcn_mfma_f32_16x16x32_bf16(af[mt], bfr[nt], acc[mt][nt], 0, 0, 0);
    __builtin_amdgcn_s_setprio(0);
  }

  // ---- epilogue
#pragma unroll
  for (int mt = 0; mt < 4; ++mt)
#pragma unroll
    for (int nt = 0; nt < 4; ++nt) {
      const int col = bcol + wn * 64 + nt * 16 + li;
      const int row0 = brow + wm * 64 + mt * 16 + g * 4;
      if (MODE == 1) {
#pragma unroll
        for (int r = 0; r < 4; ++r)
          ((float*)Cout)[(size_t)(row0 + r) * N + col] = acc[mt][nt][r];
      } else {
        const int which = col >> 10;       // 0=Q 1=K 2=V
        const int c2 = col & 1023;
        const int h = c2 >> 6, hd = c2 & 63;
        const int bb = row0 >> 11, s0 = row0 & 2047;
        if (which == 2) {
          // V -> VT-perm [B,H,HD,S-perm]: kv = s&63 lands at
          // pos = (kv&0x23)|((kv&0x10)>>2)|((kv&0x0C)<<1); r=0..3 consecutive.
          const int kv = s0 & 63;
          const int pos = (kv & 0x23) | ((kv & 0x10) >> 2) | ((kv & 0x0C) << 1);
          ushort4v st;
#pragma unroll
          for (int r = 0; r < 4; ++r) st[r] = f2bf(acc[mt][nt][r]);
          *(ushort4v*)((u16*)Cout + (size_t)3 * 8388608 +
                       (size_t)(bb * 16 + h) * 131072 + (size_t)hd * 2048 +
                       (s0 >> 6) * 64 + pos) = st;
        } else {
#pragma unroll
          for (int r = 0; r < 4; ++r) {
            float v = acc[mt][nt][r];
            if (which == 0) v *= QSCALE;
            ((u16*)Cout)[(size_t)which * 8388608 +
                         (((size_t)(bb * 16 + h) * 2048) + s0 + r) * 64 + hd] = f2bf(v);
          }
        }
      }
    }
}

// ---- causal flash attention v11: 4 blocks/CU, scheduler-aware map ---------
// HW model (confirmed rounds 2, 11, 12): block -> CU = id mod 256.
// c = id&255, k = id>>8; bh = (c&7)*8+(c>>5); r4 = (c>>3)&3; p-set per CU =
// {2r, 15-2r, 2r+1, 14-2r} -> 68 iters on every CU (4 co-resident blocks).
// Math: v9 (l via ones-MFMA, VT-perm single-b128 PV A-frags).

__global__ __launch_bounds__(256, 4) void flash_attn11(
    const u16* __restrict__ Qp, const u16* __restrict__ Kp,
    const u16* __restrict__ VTp, u16* __restrict__ Oattn)
{
  const int id = blockIdx.x;                   // 0..1023
  const int c = id & 255, k = id >> 8;
  const int bh = (c & 7) * 8 + (c >> 5);
  const int r4 = (c >> 3) & 3;
  const int base = 2 * r4 + (k >> 1);
  const int p = (k & 1) ? 15 - base : base;
  const int qbase = p * 128;
  const int njb = 2 * p + 2;

  const int t = threadIdx.x;
  const int lane = t & 63, w = t >> 6;
  const int li = lane & 15, g = lane >> 4;

  __shared__ u16 Kl[2][64 * 64];   // [buf][kv][hd], rows 128B, XOR-swizzled
  __shared__ u16 Vl[2][64 * 64];   // [buf][hd][kv-perm]

  const size_t bh_off = (size_t)bh * (2048 * 64);
  const int b = bh >> 4, h = bh & 15;
  const int ksw = (li & 7) << 3;

  short8 qc[2][2];
#pragma unroll
  for (int qs = 0; qs < 2; ++qs) {
    const u16* qp = Qp + bh_off + (size_t)(qbase + qs * 64 + w * 16 + li) * 64 + g * 8;
    qc[qs][0] = *(const short8*)qp;
    qc[qs][1] = *(const short8*)(qp + 32);
  }

  short8 onesf;
#pragma unroll
  for (int j = 0; j < 8; ++j) onesf[j] = (short)0x3F80;

  f32x4 o_acc[2][4];
  f32x4 osum[2];
#pragma unroll
  for (int qs = 0; qs < 2; ++qs) {
    osum[qs] = f32x4{0.f, 0.f, 0.f, 0.f};
#pragma unroll
    for (int i = 0; i < 4; ++i) o_acc[qs][i] = f32x4{0.f, 0.f, 0.f, 0.f};
  }
  float m_i[2] = {-1e30f, -1e30f};

  auto STAGE = [&](int jb, int s) {
#pragma unroll
    for (int L = 0; L < 2; ++L) {
      const int f = t + 256 * L;
      const int kbyte = (f * 16) ^ (((f >> 3) & 7) << 4);
      async16(Kp + bh_off + (size_t)jb * 4096 + (kbyte >> 1),
              &Kl[s][(w * 64 + 256 * L) * 8]);
      const int vrow = f >> 3;
      const int vb = ((f & 7) * 16) ^ ((vrow & 7) << 4);
      async16(VTp + bh_off + (size_t)vrow * 2048 + jb * 64 + (vb >> 1),
              &Vl[s][(w * 64 + 256 * L) * 8]);
    }
  };

  STAGE(0, 0);
  asm volatile("s_waitcnt vmcnt(0)" ::: "memory");
  __builtin_amdgcn_s_barrier();

#pragma unroll 1
  for (int i = 0; i < njb; ++i) {
    const int s = i & 1;
    if (i + 1 < njb) STAGE(i + 1, (i + 1) & 1);

    const int jb = i;
    const u16* __restrict__ Ks = &Kl[s][0];
    const u16* __restrict__ Vs = &Vl[s][0];

    f32x4 s_acc[2][4];
#pragma unroll
    for (int qs = 0; qs < 2; ++qs)
#pragma unroll
      for (int jt = 0; jt < 4; ++jt) s_acc[qs][jt] = f32x4{0.f, 0.f, 0.f, 0.f};
    __builtin_amdgcn_s_setprio(1);
#pragma unroll
    for (int kc = 0; kc < 2; ++kc)
#pragma unroll
      for (int jt = 0; jt < 4; ++jt) {
        short8 kf = *(const short8*)&Ks[(jt * 16 + li) * 64 + ((kc * 32 + g * 8) ^ ksw)];
        s_acc[0][jt] = __builtin_amdgcn_mfma_f32_16x16x32_bf16(kf, qc[0][kc], s_acc[0][jt], 0, 0, 0);
        s_acc[1][jt] = __builtin_amdgcn_mfma_f32_16x16x32_bf16(kf, qc[1][kc], s_acc[1][jt], 0, 0, 0);
      }
    __builtin_amdgcn_s_setprio(0);

    float mx[2];
    bool need = false;
#pragma unroll
    for (int qs = 0; qs < 2; ++qs) {
      if (jb * 64 + 63 > qbase + qs * 64 + w * 16) {   // wave-uniform
        const int tq = qbase + qs * 64 + w * 16 + li - jb * 64;
#pragma unroll
        for (int jt = 0; jt < 4; ++jt)
#pragma unroll
          for (int r = 0; r < 4; ++r)
            if (jt * 16 + g * 4 + r > tq) s_acc[qs][jt][r] = -1e30f;
      }
      float t0 = fmax3(s_acc[qs][0][0], s_acc[qs][0][1], s_acc[qs][0][2]);
      float t1 = fmax3(s_acc[qs][0][3], s_acc[qs][1][0], s_acc[qs][1][1]);
      float t2 = fmax3(s_acc[qs][1][2], s_acc[qs][1][3], s_acc[qs][2][0]);
      float t3 = fmax3(s_acc[qs][2][1], s_acc[qs][2][2], s_acc[qs][2][3]);
      float t4m = fmax3(s_acc[qs][3][0], s_acc[qs][3][1], s_acc[qs][3][2]);
      float m01 = fmax3(t0, t1, s_acc[qs][3][3]);
      float m23 = fmax3(t2, t3, t4m);
      float mm = fmaxf(m01, m23);
      mm = fmaxf(mm, __shfl_xor(mm, 16));
      mm = fmaxf(mm, __shfl_xor(mm, 32));
      mx[qs] = mm;
      need = need || (mm > m_i[qs] + THR_L2);
    }

    if (__any((int)need)) {
#pragma unroll
      for (int qs = 0; qs < 2; ++qs) {
        const float mn = fmaxf(m_i[qs], mx[qs]);
        const float corr = __builtin_amdgcn_exp2f(m_i[qs] - mn);
        osum[qs] *= corr;
#pragma unroll
        for (int dt = 0; dt < 4; ++dt) o_acc[qs][dt] *= corr;
        m_i[qs] = mn;
      }
    }

    short8 pf[2][2];
#pragma unroll
    for (int qs = 0; qs < 2; ++qs) {
      const float mi = m_i[qs];
#pragma unroll
      for (int jt = 0; jt < 4; ++jt)
#pragma unroll
        for (int r = 0; r < 4; ++r)
          s_acc[qs][jt][r] = __builtin_amdgcn_exp2f(s_acc[qs][jt][r] - mi);
#pragma unroll
      for (int kc = 0; kc < 2; ++kc) {
        uint4v u;
        u[0] = cvtpk(s_acc[qs][2 * kc][0], s_acc[qs][2 * kc][1]);
        u[1] = cvtpk(s_acc[qs][2 * kc][2], s_acc[qs][2 * kc][3]);
        u[2] = cvtpk(s_acc[qs][2 * kc + 1][0], s_acc[qs][2 * kc + 1][1]);
        u[3] = cvtpk(s_acc[qs][2 * kc + 1][2], s_acc[qs][2 * kc + 1][3]);
        pf[qs][kc] = __builtin_bit_cast(short8, u);
      }
    }

    __builtin_amdgcn_s_setprio(1);
#pragma unroll
    for (int kc = 0; kc < 2; ++kc) {
      osum[0] = __builtin_amdgcn_mfma_f32_16x16x32_bf16(onesf, pf[0][kc], osum[0], 0, 0, 0);
      osum[1] = __builtin_amdgcn_mfma_f32_16x16x32_bf16(onesf, pf[1][kc], osum[1], 0, 0, 0);
#pragma unroll
      for (int dt = 0; dt < 4; ++dt) {
        short8 vf = *(const short8*)&Vs[(dt * 16 + li) * 64 + ((kc * 32 + g * 8) ^ ksw)];
        o_acc[0][dt] = __builtin_amdgcn_mfma_f32_16x16x32_bf16(vf, pf[0][kc], o_acc[0][dt], 0, 0, 0);
        o_acc[1][dt] = __builtin_amdgcn_mfma_f32_16x16x32_bf16(vf, pf[1][kc], o_acc[1][dt], 0, 0, 0);
      }
    }
    __builtin_amdgcn_s_setprio(0);

    asm volatile("s_waitcnt lgkmcnt(0)" ::: "memory");
    asm volatile("s_waitcnt vmcnt(0)" ::: "memory");
    __builtin_amdgcn_s_barrier();
  }

  // ---- epilogue
#pragma unroll
  for (int qs = 0; qs < 2; ++qs) {
    const float inv_l = 1.f / osum[qs][0];
    const int qrow = qbase + qs * 64 + w * 16 + li;
    u16* op = Oattn + ((size_t)(b * 2048 + qrow)) * 1024 + h * 64;
#pragma unroll
    for (int dt = 0; dt < 4; ++dt) {
      ushort4v st;
#pragma unroll
      for (int r = 0; r < 4; ++r) st[r] = f2bf(o_acc[qs][dt][r] * inv_l);
      *(ushort4v*)(op + dt * 16 + g * 4) = st;
    }
  }
}

// ---- launch --------------------------------------------------------------

extern "C" void kernel_launch(void* const* d_in, const int* in_sizes, int n_in,
                              void* d_out, int out_size, void* d_ws, size_t ws_size,
                              hipStream_t stream) {
  const float* x  = (const float*)d_in[0];
  const float* Wq = (const float*)d_in[1];
  const float* Wk = (const float*)d_in[2];
  const float* Wv = (const float*)d_in[3];
  const float* Wo = (const float*)d_in[4];

  const size_t NX = 8388608;   // B*S*D
  const size_t NW = 1048576;   // D*D

  u16* xb  = (u16*)d_ws;
  u16* wqb = xb + NX;          // wq|wk|wv|wo contiguous
  u16* wob = wqb + 3 * NW;
  u16* Qb  = wob + NW;         // Q | K | (V slot, unused) | VT-perm
  u16* Kb  = Qb + NX;
  u16* VTb = Qb + 3 * NX;      // written directly by the QKV GEMM epilogue
  u16* attnb = Qb + 2 * NX;    // dead V-natural slot reused for attn output

  cvt_all<<<12288, 256, 0, stream>>>(x, Wq, Wk, Wv, Wo, xb);

  // fused QKV projection: grid 24x64 = 1536 = 6/CU (two balanced rounds of 3)
  gemm_t3<0><<<dim3(24, 64), 256, 0, stream>>>(xb, wqb, Qb, 8192, 3072, 1024);

  flash_attn11<<<1024, 256, 0, stream>>>(Qb, Kb, VTb, attnb);

  // output projection: grid 8x64 = 512 = 2/CU balanced
  gemm_t3<1><<<dim3(8, 64), 256, 0, stream>>>(attnb, wob, d_out, 8192, 1024, 1024);
}

// Round 17
// 150.830 us; speedup vs baseline: 1.0484x; 1.0484x over previous
//
#include <hip/hip_runtime.h>
#include <cstdint>
#include <cstddef>

typedef unsigned short u16;
typedef __attribute__((ext_vector_type(8))) short short8;
typedef __attribute__((ext_vector_type(4))) short short4v;
typedef __attribute__((ext_vector_type(8))) unsigned short ushort8v;
typedef __attribute__((ext_vector_type(4))) unsigned short ushort4v;
typedef __attribute__((ext_vector_type(4))) unsigned int uint4v;
typedef __attribute__((ext_vector_type(4))) float f32x4;

// Q is pre-scaled by 0.125 * log2(e) in the QKV GEMM epilogue, so softmax
// runs directly in the log2 domain (exp2, no per-element multiplies).
#define QSCALE 0.18033688011112042f
#define THR_L2 11.5417f   /* 8 * log2(e) defer-max threshold (T13) */

// ---- helpers -------------------------------------------------------------

__device__ __forceinline__ u16 f2bf(float f) {
  unsigned int u = __builtin_bit_cast(unsigned int, f);
  u += 0x7FFFu + ((u >> 16) & 1u);   // RNE
  return (u16)(u >> 16);
}

__device__ __forceinline__ void async16(const void* g, void* l) {
  __builtin_amdgcn_global_load_lds(
      (const __attribute__((address_space(1))) unsigned int*)g,
      (__attribute__((address_space(3))) unsigned int*)l, 16, 0, 0);
}

__device__ __forceinline__ float fmax3(float a, float b, float c) {
  float r;
  asm("v_max3_f32 %0, %1, %2, %3" : "=v"(r) : "v"(a), "v"(b), "v"(c));
  return r;
}

__device__ __forceinline__ unsigned int cvtpk(float lo, float hi) {
  unsigned int r;
  asm("v_cvt_pk_bf16_f32 %0, %1, %2" : "=v"(r) : "v"(lo), "v"(hi));
  return r;
}

// ---- fp32 -> bf16 convert (x + all 4 weights, one launch) ----------------

__global__ void cvt_all(const float* __restrict__ x, const float* __restrict__ Wq,
                        const float* __restrict__ Wk, const float* __restrict__ Wv,
                        const float* __restrict__ Wo, u16* __restrict__ out) {
  const int bid = blockIdx.x;
  const float* src;
  int i;
  size_t doff;
  if (bid < 8192) {               // x: 8.39M elems
    i = bid * 1024 + threadIdx.x * 4;
    src = x;
    doff = (size_t)i;
  } else {                        // weights: 4 x 1M elems
    const int k = bid - 8192;
    const int wsel = k >> 10;
    i = (k & 1023) * 1024 + threadIdx.x * 4;
    src = (wsel == 0) ? Wq : (wsel == 1) ? Wk : (wsel == 2) ? Wv : Wo;
    doff = 8388608 + (size_t)wsel * 1048576 + i;
  }
  float4 v = *(const float4*)(src + i);
  ushort4v o;
  o[0] = f2bf(v.x); o[1] = f2bf(v.y); o[2] = f2bf(v.z); o[3] = f2bf(v.w);
  *(ushort4v*)(out + doff) = o;
}

// ---- bf16 GEMM, counted-vmcnt TRIPLE-buffer, 2 blocks/CU -----------------
// C[M,N] = A[M,K] * W[N,K]^T.  BM=256, BN=128, BK=32, 8 waves (4M x 2N),
// per-wave 64x64 output. 3 LDS buffers (72 KB -> 2 resident blocks/CU);
// tile T+2 staged during tile T's phase; vmcnt(3) at phase heads.
// One barrier per K-tile.
// MODE 0: fused QKV — Q/K written bf16 permuted to [B,H,S,HD]; V (col>=2048)
//         written DIRECTLY in VT-perm layout (no transpose kernel); Q gets
//         QSCALE folded in.
// MODE 1: f32 output [M,N].

template<int MODE>
__global__ __launch_bounds__(512, 4) void gemm_tb(
    const u16* __restrict__ A, const u16* __restrict__ Bw,
    void* __restrict__ Cout, int M, int N, int K)
{
  const int t = threadIdx.x;
  const int lane = t & 63, w = t >> 6;        // 8 waves
  const int li = lane & 15, g = lane >> 4;
  const int wm = w >> 1, wn = w & 1;          // 4M x 2N

  // T1: XCD-aware block swizzle (nwg % 8 == 0 for all our launches)
  const int nx = gridDim.x;
  const int hwid = blockIdx.y * nx + blockIdx.x;
  const int cpx = (nx * gridDim.y) >> 3;
  const int lid = (hwid & 7) * cpx + (hwid >> 3);
  const int brow = (lid / nx) * 256, bcol = (lid % nx) * 128;

  __shared__ u16 As[3][256 * 32];   // 48 KB
  __shared__ u16 Bs[3][128 * 32];   // 24 KB

  f32x4 acc[4][4];
#pragma unroll
  for (int i = 0; i < 4; ++i)
#pragma unroll
    for (int j = 0; j < 4; ++j) acc[i][j] = f32x4{0.f, 0.f, 0.f, 0.f};

  // Staging: linear LDS dest (global_load_lds), source column pre-swizzled
  // by byte ^= ((row>>1)&3)<<4 (2-way-free on 64B rows; rule #21 pairing).
  auto STAGE = [&](int T) {
    const int b = T % 3;
    const int k0 = T * 32;
#pragma unroll
    for (int L = 0; L < 2; ++L) {
      const int f2 = t + 512 * L;
      const int row = f2 >> 2;
      const int cb = ((f2 & 3) * 16) ^ (((row >> 1) & 3) << 4);
      async16(A + (size_t)(brow + row) * K + k0 + (cb >> 1), &As[b][f2 * 8]);
    }
    const int rowb = t >> 2;
    const int cbb = ((t & 3) * 16) ^ (((rowb >> 1) & 3) << 4);
    async16(Bw + (size_t)(bcol + rowb) * K + k0 + (cbb >> 1), &Bs[b][t * 8]);
  };

  STAGE(0); STAGE(1);

  const int NT = K >> 5;                       // 32 K-tiles
  const int ksw = (g * 8) ^ (((li >> 1) & 3) << 3);   // element-space read swz

#pragma unroll 1
  for (int T = 0; T < NT; ++T) {
    // counted vmcnt: tile T's 3 loads landed; tile T+1's 3 may remain
    if (T < NT - 1) asm volatile("s_waitcnt vmcnt(3)" ::: "memory");
    else            asm volatile("s_waitcnt vmcnt(0)" ::: "memory");
    asm volatile("s_barrier" ::: "memory");    // all waves: tile T landed;
                                               // all reads of buf (T-1)%3 done
    const int b = T % 3;
    short8 af[4], bfr[4];
#pragma unroll
    for (int mt = 0; mt < 4; ++mt)
      af[mt] = *(const short8*)&As[b][(wm * 64 + mt * 16 + li) * 32 + ksw];
#pragma unroll
    for (int nt = 0; nt < 4; ++nt)
      bfr[nt] = *(const short8*)&Bs[b][(wn * 64 + nt * 16 + li) * 32 + ksw];

    if (T + 2 < NT) STAGE(T + 2);              // into buf (T-1)%3 — safe

    __builtin_amdgcn_s_setprio(1);
#pragma unroll
    for (int mt = 0; mt < 4; ++mt)
#pragma unroll
      for (int nt = 0; nt < 4; ++nt)
        acc[mt][nt] = __builtin_amdgcn_mfma_f32_16x16x32_bf16(af[mt], bfr[nt], acc[mt][nt], 0, 0, 0);
    __builtin_amdgcn_s_setprio(0);
  }

#pragma unroll
  for (int mt = 0; mt < 4; ++mt)
#pragma unroll
    for (int nt = 0; nt < 4; ++nt) {
      const int col = bcol + wn * 64 + nt * 16 + li;
      const int row0 = brow + wm * 64 + mt * 16 + g * 4;
      if (MODE == 1) {
#pragma unroll
        for (int r = 0; r < 4; ++r)
          ((float*)Cout)[(size_t)(row0 + r) * N + col] = acc[mt][nt][r];
      } else {
        const int which = col >> 10;       // 0=Q 1=K 2=V
        const int c2 = col & 1023;
        const int h = c2 >> 6, hd = c2 & 63;
        const int bb = row0 >> 11, s0 = row0 & 2047;
        if (which == 2) {
          // V -> VT-perm [B,H,HD,S-perm]: within each 64-row block,
          // kv = s&63 lands at pos = (kv&0x23)|((kv&0x10)>>2)|((kv&0x0C)<<1);
          // r=0..3 are consecutive pos -> one 8B store.
          const int kv = s0 & 63;
          const int pos = (kv & 0x23) | ((kv & 0x10) >> 2) | ((kv & 0x0C) << 1);
          ushort4v st;
#pragma unroll
          for (int r = 0; r < 4; ++r) st[r] = f2bf(acc[mt][nt][r]);
          *(ushort4v*)((u16*)Cout + (size_t)3 * 8388608 +
                       (size_t)(bb * 16 + h) * 131072 + (size_t)hd * 2048 +
                       (s0 >> 6) * 64 + pos) = st;
        } else {
#pragma unroll
          for (int r = 0; r < 4; ++r) {
            float v = acc[mt][nt][r];
            if (which == 0) v *= QSCALE;
            ((u16*)Cout)[(size_t)which * 8388608 +
                         (((size_t)(bb * 16 + h) * 2048) + s0 + r) * 64 + hd] = f2bf(v);
          }
        }
      }
    }
}

// ---- causal flash attention v11: 4 blocks/CU, scheduler-aware map ---------
// HW model (confirmed rounds 2, 11, 12): block -> CU = id mod 256.
// c = id&255, k = id>>8; bh = (c&7)*8+(c>>5); r4 = (c>>3)&3; p-set per CU =
// {2r, 15-2r, 2r+1, 14-2r} -> 68 iters on every CU (4 co-resident blocks).
// Math: v9 (l via ones-MFMA, VT-perm single-b128 PV A-frags).

__global__ __launch_bounds__(256, 4) void flash_attn11(
    const u16* __restrict__ Qp, const u16* __restrict__ Kp,
    const u16* __restrict__ VTp, u16* __restrict__ Oattn)
{
  const int id = blockIdx.x;                   // 0..1023
  const int c = id & 255, k = id >> 8;
  const int bh = (c & 7) * 8 + (c >> 5);
  const int r4 = (c >> 3) & 3;
  const int base = 2 * r4 + (k >> 1);
  const int p = (k & 1) ? 15 - base : base;
  const int qbase = p * 128;
  const int njb = 2 * p + 2;

  const int t = threadIdx.x;
  const int lane = t & 63, w = t >> 6;
  const int li = lane & 15, g = lane >> 4;

  __shared__ u16 Kl[2][64 * 64];   // [buf][kv][hd], rows 128B, XOR-swizzled
  __shared__ u16 Vl[2][64 * 64];   // [buf][hd][kv-perm]

  const size_t bh_off = (size_t)bh * (2048 * 64);
  const int b = bh >> 4, h = bh & 15;
  const int ksw = (li & 7) << 3;

  short8 qc[2][2];
#pragma unroll
  for (int qs = 0; qs < 2; ++qs) {
    const u16* qp = Qp + bh_off + (size_t)(qbase + qs * 64 + w * 16 + li) * 64 + g * 8;
    qc[qs][0] = *(const short8*)qp;
    qc[qs][1] = *(const short8*)(qp + 32);
  }

  short8 onesf;
#pragma unroll
  for (int j = 0; j < 8; ++j) onesf[j] = (short)0x3F80;

  f32x4 o_acc[2][4];
  f32x4 osum[2];
#pragma unroll
  for (int qs = 0; qs < 2; ++qs) {
    osum[qs] = f32x4{0.f, 0.f, 0.f, 0.f};
#pragma unroll
    for (int i = 0; i < 4; ++i) o_acc[qs][i] = f32x4{0.f, 0.f, 0.f, 0.f};
  }
  float m_i[2] = {-1e30f, -1e30f};

  auto STAGE = [&](int jb, int s) {
#pragma unroll
    for (int L = 0; L < 2; ++L) {
      const int f = t + 256 * L;
      const int kbyte = (f * 16) ^ (((f >> 3) & 7) << 4);
      async16(Kp + bh_off + (size_t)jb * 4096 + (kbyte >> 1),
              &Kl[s][(w * 64 + 256 * L) * 8]);
      const int vrow = f >> 3;
      const int vb = ((f & 7) * 16) ^ ((vrow & 7) << 4);
      async16(VTp + bh_off + (size_t)vrow * 2048 + jb * 64 + (vb >> 1),
              &Vl[s][(w * 64 + 256 * L) * 8]);
    }
  };

  STAGE(0, 0);
  asm volatile("s_waitcnt vmcnt(0)" ::: "memory");
  __builtin_amdgcn_s_barrier();

#pragma unroll 1
  for (int i = 0; i < njb; ++i) {
    const int s = i & 1;
    if (i + 1 < njb) STAGE(i + 1, (i + 1) & 1);

    const int jb = i;
    const u16* __restrict__ Ks = &Kl[s][0];
    const u16* __restrict__ Vs = &Vl[s][0];

    f32x4 s_acc[2][4];
#pragma unroll
    for (int qs = 0; qs < 2; ++qs)
#pragma unroll
      for (int jt = 0; jt < 4; ++jt) s_acc[qs][jt] = f32x4{0.f, 0.f, 0.f, 0.f};
    __builtin_amdgcn_s_setprio(1);
#pragma unroll
    for (int kc = 0; kc < 2; ++kc)
#pragma unroll
      for (int jt = 0; jt < 4; ++jt) {
        short8 kf = *(const short8*)&Ks[(jt * 16 + li) * 64 + ((kc * 32 + g * 8) ^ ksw)];
        s_acc[0][jt] = __builtin_amdgcn_mfma_f32_16x16x32_bf16(kf, qc[0][kc], s_acc[0][jt], 0, 0, 0);
        s_acc[1][jt] = __builtin_amdgcn_mfma_f32_16x16x32_bf16(kf, qc[1][kc], s_acc[1][jt], 0, 0, 0);
      }
    __builtin_amdgcn_s_setprio(0);

    float mx[2];
    bool need = false;
#pragma unroll
    for (int qs = 0; qs < 2; ++qs) {
      if (jb * 64 + 63 > qbase + qs * 64 + w * 16) {   // wave-uniform
        const int tq = qbase + qs * 64 + w * 16 + li - jb * 64;
#pragma unroll
        for (int jt = 0; jt < 4; ++jt)
#pragma unroll
          for (int r = 0; r < 4; ++r)
            if (jt * 16 + g * 4 + r > tq) s_acc[qs][jt][r] = -1e30f;
      }
      float t0 = fmax3(s_acc[qs][0][0], s_acc[qs][0][1], s_acc[qs][0][2]);
      float t1 = fmax3(s_acc[qs][0][3], s_acc[qs][1][0], s_acc[qs][1][1]);
      float t2 = fmax3(s_acc[qs][1][2], s_acc[qs][1][3], s_acc[qs][2][0]);
      float t3 = fmax3(s_acc[qs][2][1], s_acc[qs][2][2], s_acc[qs][2][3]);
      float t4m = fmax3(s_acc[qs][3][0], s_acc[qs][3][1], s_acc[qs][3][2]);
      float m01 = fmax3(t0, t1, s_acc[qs][3][3]);
      float m23 = fmax3(t2, t3, t4m);
      float mm = fmaxf(m01, m23);
      mm = fmaxf(mm, __shfl_xor(mm, 16));
      mm = fmaxf(mm, __shfl_xor(mm, 32));
      mx[qs] = mm;
      need = need || (mm > m_i[qs] + THR_L2);
    }

    if (__any((int)need)) {
#pragma unroll
      for (int qs = 0; qs < 2; ++qs) {
        const float mn = fmaxf(m_i[qs], mx[qs]);
        const float corr = __builtin_amdgcn_exp2f(m_i[qs] - mn);
        osum[qs] *= corr;
#pragma unroll
        for (int dt = 0; dt < 4; ++dt) o_acc[qs][dt] *= corr;
        m_i[qs] = mn;
      }
    }

    short8 pf[2][2];
#pragma unroll
    for (int qs = 0; qs < 2; ++qs) {
      const float mi = m_i[qs];
#pragma unroll
      for (int jt = 0; jt < 4; ++jt)
#pragma unroll
        for (int r = 0; r < 4; ++r)
          s_acc[qs][jt][r] = __builtin_amdgcn_exp2f(s_acc[qs][jt][r] - mi);
#pragma unroll
      for (int kc = 0; kc < 2; ++kc) {
        uint4v u;
        u[0] = cvtpk(s_acc[qs][2 * kc][0], s_acc[qs][2 * kc][1]);
        u[1] = cvtpk(s_acc[qs][2 * kc][2], s_acc[qs][2 * kc][3]);
        u[2] = cvtpk(s_acc[qs][2 * kc + 1][0], s_acc[qs][2 * kc + 1][1]);
        u[3] = cvtpk(s_acc[qs][2 * kc + 1][2], s_acc[qs][2 * kc + 1][3]);
        pf[qs][kc] = __builtin_bit_cast(short8, u);
      }
    }

    __builtin_amdgcn_s_setprio(1);
#pragma unroll
    for (int kc = 0; kc < 2; ++kc) {
      osum[0] = __builtin_amdgcn_mfma_f32_16x16x32_bf16(onesf, pf[0][kc], osum[0], 0, 0, 0);
      osum[1] = __builtin_amdgcn_mfma_f32_16x16x32_bf16(onesf, pf[1][kc], osum[1], 0, 0, 0);
#pragma unroll
      for (int dt = 0; dt < 4; ++dt) {
        short8 vf = *(const short8*)&Vs[(dt * 16 + li) * 64 + ((kc * 32 + g * 8) ^ ksw)];
        o_acc[0][dt] = __builtin_amdgcn_mfma_f32_16x16x32_bf16(vf, pf[0][kc], o_acc[0][dt], 0, 0, 0);
        o_acc[1][dt] = __builtin_amdgcn_mfma_f32_16x16x32_bf16(vf, pf[1][kc], o_acc[1][dt], 0, 0, 0);
      }
    }
    __builtin_amdgcn_s_setprio(0);

    asm volatile("s_waitcnt lgkmcnt(0)" ::: "memory");
    asm volatile("s_waitcnt vmcnt(0)" ::: "memory");
    __builtin_amdgcn_s_barrier();
  }

  // ---- epilogue
#pragma unroll
  for (int qs = 0; qs < 2; ++qs) {
    const float inv_l = 1.f / osum[qs][0];
    const int qrow = qbase + qs * 64 + w * 16 + li;
    u16* op = Oattn + ((size_t)(b * 2048 + qrow)) * 1024 + h * 64;
#pragma unroll
    for (int dt = 0; dt < 4; ++dt) {
      ushort4v st;
#pragma unroll
      for (int r = 0; r < 4; ++r) st[r] = f2bf(o_acc[qs][dt][r] * inv_l);
      *(ushort4v*)(op + dt * 16 + g * 4) = st;
    }
  }
}

// ---- launch --------------------------------------------------------------

extern "C" void kernel_launch(void* const* d_in, const int* in_sizes, int n_in,
                              void* d_out, int out_size, void* d_ws, size_t ws_size,
                              hipStream_t stream) {
  const float* x  = (const float*)d_in[0];
  const float* Wq = (const float*)d_in[1];
  const float* Wk = (const float*)d_in[2];
  const float* Wv = (const float*)d_in[3];
  const float* Wo = (const float*)d_in[4];

  const size_t NX = 8388608;   // B*S*D
  const size_t NW = 1048576;   // D*D

  u16* xb  = (u16*)d_ws;
  u16* wqb = xb + NX;          // wq|wk|wv|wo contiguous
  u16* wob = wqb + 3 * NW;
  u16* Qb  = wob + NW;         // Q | K | (V slot, unused) | VT-perm
  u16* Kb  = Qb + NX;
  u16* VTb = Qb + 3 * NX;      // written directly by the QKV GEMM epilogue
  u16* attnb = Qb + 2 * NX;    // dead V-natural slot reused for attn output

  cvt_all<<<12288, 256, 0, stream>>>(x, Wq, Wk, Wv, Wo, xb);

  // fused QKV projection: grid 24x32 = 768 (round-12 proven best)
  gemm_tb<0><<<dim3(24, 32), 512, 0, stream>>>(xb, wqb, Qb, 8192, 3072, 1024);

  flash_attn11<<<1024, 256, 0, stream>>>(Qb, Kb, VTb, attnb);

  // output projection: grid 8x32 = 256 (round-12 proven best)
  gemm_tb<1><<<dim3(8, 32), 512, 0, stream>>>(attnb, wob, d_out, 8192, 1024, 1024);
}